// Round 2
// baseline (697.709 us; speedup 1.0000x reference)
//
#include <hip/hip_runtime.h>
#include <stdint.h>

// Fused LoRA linear: out[m,o] = bias[o] + 2 * sum_r (sum_i x[m,i]*A[r,i]) * B[o,r]
// x: [8192, 4096] f32, A: [16, 4096] f32, B: [4096, 16] f32, bias: [4096] f32
//
// Single kernel: each block owns 8 token rows. Phase A computes t[8][16] =
// 2*(x_rows @ A^T) (verified structure: A chunk double-buffered in LDS via
// global_load_lds width=16, x on the vmcnt prefetch path, butterfly reduce),
// landing t in LDS. Phase B streams the block's own 8x4096 output slice.
//
// ROUND-1 LESSON (counter-verified): __builtin_nontemporal_{load,store} on
// the streamed x/out arrays caused ~3-4x HBM traffic amplification
// (FETCH 568 MB vs 134 MB ideal, WRITE 393 MB vs 134 MB ideal) -- on gfx950
// the L2 is the read-combiner/write-coalescer for streaming traffic; nt
// bypasses it and hits HBM at sub-line granularity. Plain loads/stores here.

constexpr int IN_F  = 4096;
constexpr int OUT_F = 4096;
constexpr int RANK  = 16;
constexpr int M_TOT = 4 * 2048;           // 8192 token rows
constexpr float SCALING = 2.0f;           // ALPHA / R

typedef const __attribute__((address_space(1))) void* as1_cvp;
typedef __attribute__((address_space(3))) void*       as3_vp;

__global__ __launch_bounds__(256, 4) void lora_fused(
    const float* __restrict__ x, const float* __restrict__ A,
    const float* __restrict__ B, const float* __restrict__ bias,
    float* __restrict__ out)
{
    __shared__ float4 As[2][RANK][64];    // 2 x 16 KB double-buffered A chunk
    __shared__ float  t_lds[8][RANK];     // block-local t tile (512 B)

    const int lane = threadIdx.x & 63;
    const int wave = threadIdx.x >> 6;
    const int mblk = blockIdx.x * 8;      // first token row of this block
    const int row0 = mblk + wave * 2;     // this wave's 2 rows

    const float4* __restrict__ A4 = (const float4*)A;
    const float4* __restrict__ x0 = (const float4*)(x + (size_t)row0 * IN_F);
    const float4* __restrict__ x1 = (const float4*)(x + (size_t)(row0 + 1) * IN_F);

    // ---------------- Phase A: t = 2 * (x_rows @ A^T) ----------------
    float acc0[RANK], acc1[RANK];
#pragma unroll
    for (int r = 0; r < RANK; ++r) { acc0[r] = 0.0f; acc1[r] = 0.0f; }

    // Stage j=0 into buf 0; prefetch x chunk 0.
#pragma unroll
    for (int rr = 0; rr < 4; ++rr) {
        const int r = wave * 4 + rr;
        __builtin_amdgcn_global_load_lds((as1_cvp)(A4 + (size_t)r * (IN_F / 4) + lane),
                                         (as3_vp)(&As[0][r][0]), 16, 0, 0);
    }
    float4 xc0 = x0[lane];
    float4 xc1 = x1[lane];
    __syncthreads();

    int buf = 0;
#pragma unroll 1
    for (int j = 0; j < 16; ++j) {
        float4 xn0, xn1;
        if (j < 15) {
            const int c4 = (j + 1) * 64 + lane;
#pragma unroll
            for (int rr = 0; rr < 4; ++rr) {
                const int r = wave * 4 + rr;
                __builtin_amdgcn_global_load_lds(
                    (as1_cvp)(A4 + (size_t)r * (IN_F / 4) + c4),
                    (as3_vp)(&As[buf ^ 1][r][0]), 16, 0, 0);
            }
            xn0 = x0[c4];
            xn1 = x1[c4];
        }

#pragma unroll
        for (int r = 0; r < RANK; ++r) {
            const float4 av = As[buf][r][lane];   // ds_read_b128
            acc0[r] += xc0.x * av.x;
            acc0[r] += xc0.y * av.y;
            acc0[r] += xc0.z * av.z;
            acc0[r] += xc0.w * av.w;
            acc1[r] += xc1.x * av.x;
            acc1[r] += xc1.y * av.y;
            acc1[r] += xc1.z * av.z;
            acc1[r] += xc1.w * av.w;
        }

        if (j < 15) {
            __syncthreads();   // all waves done reading As[buf]; staging drained
            buf ^= 1;
            xc0 = xn0;
            xc1 = xn1;
        }
    }

    // Cross-lane butterfly reduce (64 lanes) for each of the 2x16 sums;
    // land t in LDS (block-local).
#pragma unroll
    for (int p = 0; p < 2; ++p) {
        float out_v = 0.0f;
#pragma unroll
        for (int r = 0; r < RANK; ++r) {
            float v = (p == 0) ? acc0[r] : acc1[r];
#pragma unroll
            for (int s = 1; s < 64; s <<= 1)
                v += __shfl_xor(v, s, 64);
            out_v = (lane == r) ? v : out_v;
        }
        if (lane < RANK)
            t_lds[wave * 2 + p][lane] = SCALING * out_v;
    }
    __syncthreads();

    // ---------------- Phase B: out_rows = t @ B^T + bias ----------------
    // 4 column-chunks of 1024; thread owns 4 cols per chunk, all 8 rows.
    const float4* __restrict__ B4 = (const float4*)B;
#pragma unroll 1
    for (int c = 0; c < 4; ++c) {
        const int o0 = c * 1024 + threadIdx.x * 4;   // first owned column

        // b[q][rr] = B[o0+q][4*rr .. 4*rr+3]  (L2-resident after first pass)
        float4 b[4][4];
#pragma unroll
        for (int q = 0; q < 4; ++q)
#pragma unroll
            for (int rr = 0; rr < 4; ++rr)
                b[q][rr] = B4[(size_t)(o0 + q) * 4 + rr];

        const float4 bs = *(const float4*)(bias + o0);

#pragma unroll
        for (int mi = 0; mi < 8; ++mi) {
            // broadcast reads (same address across wave -> conflict-free)
            const float4 tv0 = *(const float4*)&t_lds[mi][0];
            const float4 tv1 = *(const float4*)&t_lds[mi][4];
            const float4 tv2 = *(const float4*)&t_lds[mi][8];
            const float4 tv3 = *(const float4*)&t_lds[mi][12];
            const float4 tv[4] = {tv0, tv1, tv2, tv3};

            float v[4] = {bs.x, bs.y, bs.z, bs.w};
#pragma unroll
            for (int q = 0; q < 4; ++q) {
#pragma unroll
                for (int rr = 0; rr < 4; ++rr) {
                    v[q] += b[q][rr].x * tv[rr].x;
                    v[q] += b[q][rr].y * tv[rr].y;
                    v[q] += b[q][rr].z * tv[rr].z;
                    v[q] += b[q][rr].w * tv[rr].w;
                }
            }
            float4 o4 = {v[0], v[1], v[2], v[3]};
            *(float4*)(out + (size_t)(mblk + mi) * OUT_F + o0) = o4;
        }
    }
}

extern "C" void kernel_launch(void* const* d_in, const int* in_sizes, int n_in,
                              void* d_out, int out_size, void* d_ws, size_t ws_size,
                              hipStream_t stream) {
    const float* x    = (const float*)d_in[0];  // [8192, 4096]
    const float* A    = (const float*)d_in[1];  // [16, 4096]
    const float* B    = (const float*)d_in[2];  // [4096, 16]
    const float* bias = (const float*)d_in[3];  // [4096]
    float* out = (float*)d_out;                 // [8192, 4096]
    (void)d_ws; (void)ws_size;                  // t never leaves LDS

    lora_fused<<<dim3(M_TOT / 8), dim3(256), 0, stream>>>(x, A, B, bias, out);
}

// Round 3
// 312.000 us; speedup vs baseline: 2.2362x; 2.2362x over previous
//
#include <hip/hip_runtime.h>
#include <stdint.h>

// LoRA linear, SPLIT structure (counter-verified better than fused):
//   phase1: t = 2 * (x @ A^T)     [8192,16]  -- read-bound (134 MB x)
//   phase2: out = t @ B^T + bias  [8192,4096] -- write-bound (134 MB out)
//
// ROUND 1+2 LESSON (counter-verified): fusing the phases into one kernel
// causes 3-6x HBM traffic amplification (FETCH up to 884 MB vs 135 MB ideal,
// WRITE up to 697 MB vs 134 MB ideal): with the x read-stream and out
// write-stream both flowing through the per-XCD L2 while every co-resident
// block re-reads the A/B panels, the panels thrash. Split keeps each
// phase's L2 working set unidirectional + small. Nontemporal hints were NOT
// the cause (removing them made fused WORSE -- they partially shielded L2).
//
// THIS ROUND: phase 1 rewritten barrier-free. The old per-j __syncthreads
// (16/block) each forced a full vmcnt(0) drain of all outstanding loads ->
// bursty lockstep memory demand. A is only 256 KB = permanently L2-resident
// (per-j 16 KB chunk is L1-resident per CU), so LDS staging buys nothing:
// load A fragments straight to VGPRs (coalesced 1 KB/instr), keep each wave
// fully self-paced with a one-chunk x prefetch. Zero barriers, zero LDS.
// Phase 2 byte-identical to the verified round-0 version.

constexpr int IN_F  = 4096;
constexpr int OUT_F = 4096;
constexpr int RANK  = 16;
constexpr int M_TOT = 4 * 2048;           // 8192 token rows
constexpr float SCALING = 2.0f;           // ALPHA / R

// ---------------- Kernel 1: t = 2 * (x @ A^T), barrier-free ----------------
// block = 256 (4 waves); wave handles 2 rows -> 8 rows/block; grid 1024.
// Per j-chunk (256 cols): lane loads A[r][j*256+lane*4 ..+3] for r=0..15 in
// two groups of 8 (keeps VGPR ~95, 8 loads in flight), x prefetched one
// chunk ahead. No __syncthreads anywhere -> no vmcnt(0) drains -> smooth
// self-paced streaming of x at HBM BW.
__global__ __launch_bounds__(256, 4) void lora_phase1(
    const float* __restrict__ x, const float* __restrict__ A,
    float* __restrict__ t)
{
    const int lane = threadIdx.x & 63;
    const int wave = threadIdx.x >> 6;
    const int row0 = blockIdx.x * 8 + wave * 2;

    const float4* __restrict__ A4 = (const float4*)A;
    const float4* __restrict__ x0 = (const float4*)(x + (size_t)row0 * IN_F);
    const float4* __restrict__ x1 = (const float4*)(x + (size_t)(row0 + 1) * IN_F);

    float acc0[RANK], acc1[RANK];
#pragma unroll
    for (int r = 0; r < RANK; ++r) { acc0[r] = 0.0f; acc1[r] = 0.0f; }

    float4 xc0 = x0[lane];
    float4 xc1 = x1[lane];

#pragma unroll 1
    for (int j = 0; j < 16; ++j) {
        float4 xn0, xn1;
        if (j < 15) {
            const int c4 = (j + 1) * 64 + lane;
            xn0 = x0[c4];
            xn1 = x1[c4];
        }
        const int a0 = j * 64 + lane;

        // group 0: ranks 0..7
        float4 av[8];
#pragma unroll
        for (int r = 0; r < 8; ++r)
            av[r] = A4[(size_t)r * (IN_F / 4) + a0];
#pragma unroll
        for (int r = 0; r < 8; ++r) {
            acc0[r] += xc0.x * av[r].x;
            acc0[r] += xc0.y * av[r].y;
            acc0[r] += xc0.z * av[r].z;
            acc0[r] += xc0.w * av[r].w;
            acc1[r] += xc1.x * av[r].x;
            acc1[r] += xc1.y * av[r].y;
            acc1[r] += xc1.z * av[r].z;
            acc1[r] += xc1.w * av[r].w;
        }
        // group 1: ranks 8..15
#pragma unroll
        for (int r = 0; r < 8; ++r)
            av[r] = A4[(size_t)(r + 8) * (IN_F / 4) + a0];
#pragma unroll
        for (int r = 0; r < 8; ++r) {
            acc0[r + 8] += xc0.x * av[r].x;
            acc0[r + 8] += xc0.y * av[r].y;
            acc0[r + 8] += xc0.z * av[r].z;
            acc0[r + 8] += xc0.w * av[r].w;
            acc1[r + 8] += xc1.x * av[r].x;
            acc1[r + 8] += xc1.y * av[r].y;
            acc1[r + 8] += xc1.z * av[r].z;
            acc1[r + 8] += xc1.w * av[r].w;
        }

        if (j < 15) {
            xc0 = xn0;
            xc1 = xn1;
        }
    }

    // Cross-lane butterfly reduce (64 lanes) for each of the 2x16 sums.
#pragma unroll
    for (int p = 0; p < 2; ++p) {
        float out_v = 0.0f;
#pragma unroll
        for (int r = 0; r < RANK; ++r) {
            float v = (p == 0) ? acc0[r] : acc1[r];
#pragma unroll
            for (int s = 1; s < 64; s <<= 1)
                v += __shfl_xor(v, s, 64);
            out_v = (lane == r) ? v : out_v;
        }
        if (lane < RANK)
            t[(size_t)(row0 + p) * RANK + lane] = SCALING * out_v;
    }
}

// ---------------- Kernel 2: out = t @ B^T + bias ----------------
// (byte-identical to the verified round-0 version)
// block = 256; thread owns 4 cols x 4 rows. grid (4, 2048) = 8192 blocks.
// All 32 float4 loads issued before one wait, then 64 FMAs and 4 coalesced
// float4 stores. Store-throughput bound.
__global__ __launch_bounds__(256) void lora_phase2(
    const float* __restrict__ t, const float* __restrict__ B,
    const float* __restrict__ bias, float* __restrict__ out)
{
    const int o0 = blockIdx.x * 1024 + threadIdx.x * 4;  // first owned column
    const int m0 = blockIdx.y * 4;                       // first row

    const float4* __restrict__ B4 = (const float4*)B;
    const float4* __restrict__ t4 = (const float4*)t;

    // b[q][rr] = B[o0+q][4*rr .. 4*rr+3]
    float4 b[4][4];
#pragma unroll
    for (int q = 0; q < 4; ++q)
#pragma unroll
        for (int rr = 0; rr < 4; ++rr)
            b[q][rr] = B4[(size_t)(o0 + q) * 4 + rr];

    // t rows for this tile (uniform across block -> scalar loads)
    float4 tv[4][4];
#pragma unroll
    for (int mi = 0; mi < 4; ++mi)
#pragma unroll
        for (int rr = 0; rr < 4; ++rr)
            tv[mi][rr] = t4[(size_t)(m0 + mi) * 4 + rr];

    const float4 bs = *(const float4*)(bias + o0);

#pragma unroll
    for (int mi = 0; mi < 4; ++mi) {
        float v[4] = {bs.x, bs.y, bs.z, bs.w};
#pragma unroll
        for (int q = 0; q < 4; ++q) {
#pragma unroll
            for (int rr = 0; rr < 4; ++rr) {
                v[q] += b[q][rr].x * tv[mi][rr].x;
                v[q] += b[q][rr].y * tv[mi][rr].y;
                v[q] += b[q][rr].z * tv[mi][rr].z;
                v[q] += b[q][rr].w * tv[mi][rr].w;
            }
        }
        float4 o4 = {v[0], v[1], v[2], v[3]};
        *(float4*)(out + (size_t)(m0 + mi) * OUT_F + o0) = o4;
    }
}

extern "C" void kernel_launch(void* const* d_in, const int* in_sizes, int n_in,
                              void* d_out, int out_size, void* d_ws, size_t ws_size,
                              hipStream_t stream) {
    const float* x    = (const float*)d_in[0];  // [8192, 4096]
    const float* A    = (const float*)d_in[1];  // [16, 4096]
    const float* B    = (const float*)d_in[2];  // [4096, 16]
    const float* bias = (const float*)d_in[3];  // [4096]
    float* out = (float*)d_out;                 // [8192, 4096]
    float* t   = (float*)d_ws;                  // [8192, 16] scratch (512 KB)

    // Phase 1: t = 2 * x @ A^T   (barrier-free, self-paced streaming)
    lora_phase1<<<dim3(M_TOT / 8), dim3(256), 0, stream>>>(x, A, t);
    // Phase 2: out = t @ B^T + bias
    lora_phase2<<<dim3(OUT_F / 1024, M_TOT / 4), dim3(256), 0, stream>>>(t, B, bias, out);
}

// Round 4
// 262.352 us; speedup vs baseline: 2.6594x; 1.1892x over previous
//
#include <hip/hip_runtime.h>
#include <stdint.h>

// LoRA linear, SPLIT structure:
//   phase1: t = 2 * (x @ A^T)     [8192,16]   -- read-stream x (134 MB)
//   phase2: out = t @ B^T + bias  [8192,4096] -- write-stream out (134 MB)
//
// MODEL (round-3 counters): phase1 is bound by per-CU vmem-path bytes/iter
// (~23 B/cyc/CU effective). Round-3's per-wave A loads replicated the 16 KB
// A-chunk 16x per CU per iter (288 KB/CU/iter -> 82 us, independent of
// HBM-vs-L3 sourcing). Fix: stage A once per 512-thread block (16 rows) via
// global_load_lds, double-buffered -> 2 blocks/CU -> 64 KB/CU/iter.
//
// Phase2 was L1-transaction bound: per-thread-contiguous B reads are
// stride-256B across lanes = 64 cacheline touches per load instr (~55 us of
// L1 churn per CU). Fix: transpose B once into ws (BT[16][4096], 256 KB);
// B-fragments become lane-contiguous float4 loads. Fallback to the old
// strided phase2 if ws_size < 768 KB.

constexpr int IN_F  = 4096;
constexpr int OUT_F = 4096;
constexpr int RANK  = 16;
constexpr int M_TOT = 4 * 2048;           // 8192 token rows
constexpr float SCALING = 2.0f;           // ALPHA / R

typedef const __attribute__((address_space(1))) void* as1_cvp;
typedef __attribute__((address_space(3))) void*       as3_vp;
typedef float f32x4 __attribute__((ext_vector_type(4)));

// ---------------- Kernel 1: t = 2 * (x @ A^T) ----------------
// block = 512 (8 waves); wave handles 2 rows -> 16 rows/block; grid 512
// (= 2 blocks/CU, 16 waves/CU). Per j-chunk (256 cols): the 16 KB A-chunk
// is staged ONCE per block (wave w stages ranks 2w, 2w+1 via
// global_load_lds width=16, dst = base + lane*16 = consume layout),
// double-buffered. x prefetched one chunk ahead; the end-of-iter
// __syncthreads' vmcnt drain covers staging + x issued ~1300 cyc earlier.
__global__ __launch_bounds__(512, 4) void lora_phase1(
    const float* __restrict__ x, const float* __restrict__ A,
    float* __restrict__ t)
{
    __shared__ float4 As[2][RANK][64];    // 2 x 16 KB
    const int lane = threadIdx.x & 63;
    const int wave = threadIdx.x >> 6;    // 0..7
    const int row0 = blockIdx.x * 16 + wave * 2;

    const float4* __restrict__ A4 = (const float4*)A;
    const float4* __restrict__ x0 = (const float4*)(x + (size_t)row0 * IN_F);
    const float4* __restrict__ x1 = (const float4*)(x + (size_t)(row0 + 1) * IN_F);

    float acc0[RANK], acc1[RANK];
#pragma unroll
    for (int r = 0; r < RANK; ++r) { acc0[r] = 0.0f; acc1[r] = 0.0f; }

    // Stage j=0 into buf 0 (wave w -> ranks 2w, 2w+1); prefetch x chunk 0.
#pragma unroll
    for (int rr = 0; rr < 2; ++rr) {
        const int r = wave * 2 + rr;
        __builtin_amdgcn_global_load_lds((as1_cvp)(A4 + (size_t)r * (IN_F / 4) + lane),
                                         (as3_vp)(&As[0][r][0]), 16, 0, 0);
    }
    float4 xc0 = x0[lane];
    float4 xc1 = x1[lane];
    __syncthreads();

    int buf = 0;
#pragma unroll 1
    for (int j = 0; j < 16; ++j) {
        float4 xn0, xn1;
        if (j < 15) {
            const int c4 = (j + 1) * 64 + lane;
#pragma unroll
            for (int rr = 0; rr < 2; ++rr) {
                const int r = wave * 2 + rr;
                __builtin_amdgcn_global_load_lds(
                    (as1_cvp)(A4 + (size_t)r * (IN_F / 4) + c4),
                    (as3_vp)(&As[buf ^ 1][r][0]), 16, 0, 0);
            }
            xn0 = x0[c4];
            xn1 = x1[c4];
        }

#pragma unroll
        for (int r = 0; r < RANK; ++r) {
            const float4 av = As[buf][r][lane];   // ds_read_b128, conflict-free
            acc0[r] += xc0.x * av.x;
            acc0[r] += xc0.y * av.y;
            acc0[r] += xc0.z * av.z;
            acc0[r] += xc0.w * av.w;
            acc1[r] += xc1.x * av.x;
            acc1[r] += xc1.y * av.y;
            acc1[r] += xc1.z * av.z;
            acc1[r] += xc1.w * av.w;
        }

        if (j < 15) {
            __syncthreads();   // all waves done reading As[buf]; staging drained
            buf ^= 1;
            xc0 = xn0;
            xc1 = xn1;
        }
    }

    // Cross-lane butterfly reduce (64 lanes) for each of the 2x16 sums.
#pragma unroll
    for (int p = 0; p < 2; ++p) {
        float out_v = 0.0f;
#pragma unroll
        for (int r = 0; r < RANK; ++r) {
            float v = (p == 0) ? acc0[r] : acc1[r];
#pragma unroll
            for (int s = 1; s < 64; s <<= 1)
                v += __shfl_xor(v, s, 64);
            out_v = (lane == r) ? v : out_v;
        }
        if (lane < RANK)
            t[(size_t)(row0 + p) * RANK + lane] = SCALING * out_v;
    }
}

// ---------------- Kernel 1.5: BT[r][o] = B[o][r] ----------------
// 256 KB one-shot. Reads fully coalesced (float4/thread); writes are 4
// scalar stores, contiguous across lanes (256 B/instr). ~2-4 us.
__global__ __launch_bounds__(256) void transpose_B(
    const float* __restrict__ B, float* __restrict__ BT)
{
    const int id = blockIdx.x * 256 + threadIdx.x;   // 0..16383
    const float4 v = ((const float4*)B)[id];         // B[o][4k..4k+3]
    const int o = id >> 2;
    const int k = id & 3;
    BT[(size_t)(4 * k + 0) * OUT_F + o] = v.x;
    BT[(size_t)(4 * k + 1) * OUT_F + o] = v.y;
    BT[(size_t)(4 * k + 2) * OUT_F + o] = v.z;
    BT[(size_t)(4 * k + 3) * OUT_F + o] = v.w;
}

// ---------------- Kernel 2 (BT path): out = t @ B^T + bias ----------------
// block = 256; thread owns 4 cols x 4 rows; grid (4, 2048). b-loads are now
// lane-contiguous float4 (1 KB/instr), killing the L1-transaction churn.
__global__ __launch_bounds__(256) void lora_phase2t(
    const float* __restrict__ t, const float* __restrict__ BT,
    const float* __restrict__ bias, float* __restrict__ out)
{
    const int o0 = blockIdx.x * 1024 + threadIdx.x * 4;  // first owned column
    const int m0 = blockIdx.y * 4;                       // first row

    const f32x4* __restrict__ BT4 = (const f32x4*)BT;
    const float4* __restrict__ t4 = (const float4*)t;

    // b[r] = BT[r][o0..o0+3] -- lanes contiguous, coalesced
    f32x4 b[16];
#pragma unroll
    for (int r = 0; r < 16; ++r)
        b[r] = BT4[(size_t)r * (OUT_F / 4) + (o0 >> 2)];

    // t rows for this tile (uniform across block -> scalar loads)
    float4 tv[4][4];
#pragma unroll
    for (int mi = 0; mi < 4; ++mi)
#pragma unroll
        for (int rr = 0; rr < 4; ++rr)
            tv[mi][rr] = t4[(size_t)(m0 + mi) * 4 + rr];

    const f32x4 bs = *(const f32x4*)(bias + o0);

#pragma unroll
    for (int mi = 0; mi < 4; ++mi) {
        f32x4 v = bs;
#pragma unroll
        for (int rr = 0; rr < 4; ++rr) {
            v += b[4 * rr + 0] * tv[mi][rr].x;
            v += b[4 * rr + 1] * tv[mi][rr].y;
            v += b[4 * rr + 2] * tv[mi][rr].z;
            v += b[4 * rr + 3] * tv[mi][rr].w;
        }
        *(f32x4*)(out + (size_t)(m0 + mi) * OUT_F + o0) = v;
    }
}

// ---------------- Kernel 2 (fallback, ws too small): old strided-B ----------
__global__ __launch_bounds__(256) void lora_phase2(
    const float* __restrict__ t, const float* __restrict__ B,
    const float* __restrict__ bias, float* __restrict__ out)
{
    const int o0 = blockIdx.x * 1024 + threadIdx.x * 4;
    const int m0 = blockIdx.y * 4;

    const float4* __restrict__ B4 = (const float4*)B;
    const float4* __restrict__ t4 = (const float4*)t;

    float4 b[4][4];
#pragma unroll
    for (int q = 0; q < 4; ++q)
#pragma unroll
        for (int rr = 0; rr < 4; ++rr)
            b[q][rr] = B4[(size_t)(o0 + q) * 4 + rr];

    float4 tv[4][4];
#pragma unroll
    for (int mi = 0; mi < 4; ++mi)
#pragma unroll
        for (int rr = 0; rr < 4; ++rr)
            tv[mi][rr] = t4[(size_t)(m0 + mi) * 4 + rr];

    const float4 bs = *(const float4*)(bias + o0);

#pragma unroll
    for (int mi = 0; mi < 4; ++mi) {
        float v[4] = {bs.x, bs.y, bs.z, bs.w};
#pragma unroll
        for (int q = 0; q < 4; ++q) {
#pragma unroll
            for (int rr = 0; rr < 4; ++rr) {
                v[q] += b[q][rr].x * tv[mi][rr].x;
                v[q] += b[q][rr].y * tv[mi][rr].y;
                v[q] += b[q][rr].z * tv[mi][rr].z;
                v[q] += b[q][rr].w * tv[mi][rr].w;
            }
        }
        float4 o4 = {v[0], v[1], v[2], v[3]};
        *(float4*)(out + (size_t)(m0 + mi) * OUT_F + o0) = o4;
    }
}

extern "C" void kernel_launch(void* const* d_in, const int* in_sizes, int n_in,
                              void* d_out, int out_size, void* d_ws, size_t ws_size,
                              hipStream_t stream) {
    const float* x    = (const float*)d_in[0];  // [8192, 4096]
    const float* A    = (const float*)d_in[1];  // [16, 4096]
    const float* B    = (const float*)d_in[2];  // [4096, 16]
    const float* bias = (const float*)d_in[3];  // [4096]
    float* out = (float*)d_out;                 // [8192, 4096]
    float* t   = (float*)d_ws;                  // [8192, 16] scratch (512 KB)

    const size_t need_bt = (size_t)(M_TOT * RANK + RANK * OUT_F) * sizeof(float);
    const bool use_bt = ws_size >= need_bt;     // 768 KB
    float* BT = t + (size_t)M_TOT * RANK;       // [16, 4096] (256 KB)

    if (use_bt)
        transpose_B<<<dim3(64), dim3(256), 0, stream>>>(B, BT);

    // Phase 1: t = 2 * x @ A^T  (16 rows/block, A staged once per block)
    lora_phase1<<<dim3(M_TOT / 16), dim3(512), 0, stream>>>(x, A, t);

    // Phase 2: out = t @ B^T + bias
    if (use_bt)
        lora_phase2t<<<dim3(OUT_F / 1024, M_TOT / 4), dim3(256), 0, stream>>>(t, BT, bias, out);
    else
        lora_phase2<<<dim3(OUT_F / 1024, M_TOT / 4), dim3(256), 0, stream>>>(t, B, bias, out);
}

// Round 5
// 255.826 us; speedup vs baseline: 2.7273x; 1.0255x over previous
//
#include <hip/hip_runtime.h>
#include <stdint.h>

// LoRA linear, SPLIT structure (counter-verified in rounds 1-4):
//   phase1: t = 2 * (x @ A^T)     [8192,16]   -- read-stream x (134 MB)
//   phase2: out = t @ B^T + bias  [8192,4096] -- write-stream out (134 MB)
//
// MODEL (rounds 3-4, predictive): both phases are bound by per-CU
// vector-memory-path bytes (~23 B/cyc/CU effective through L1/L2), not HBM.
// Levers applied this round:
//  - phase1: 32 rows/block (4 rows/wave) -> A-staging drops from 134 MB
//    (= x traffic!) to 67 MB; per-CU per-iter 48 KB vs 64 KB.
//  - phase2: 16 rows/block -> per-block b[16] fragment (64 KB of BT) is
//    amortized over 4x more output; per-CU BT traffic 2 MB -> 512 KB.
//  - B-transpose folded into the tail of phase1 blocks 0..31 (one less
//    launch; BT only needed after phase1 retires anyway).

constexpr int IN_F  = 4096;
constexpr int OUT_F = 4096;
constexpr int RANK  = 16;
constexpr int M_TOT = 8192;               // token rows
constexpr float SCALING = 2.0f;           // ALPHA / R

typedef const __attribute__((address_space(1))) void* as1_cvp;
typedef __attribute__((address_space(3))) void*       as3_vp;
typedef float f32x4 __attribute__((ext_vector_type(4)));

// ---------------- Kernel 1: t = 2 * (x @ A^T)  (+ B transpose tail) --------
// block = 512 (8 waves); wave handles 4 rows -> 32 rows/block; grid 256
// (1 block/CU, 8 waves/CU). Per j-chunk (256 cols): 16 KB A-chunk staged
// ONCE per block (wave w stages ranks 2w, 2w+1 via global_load_lds width=16,
// dst = base + lane*16 = consume layout), double-buffered. x prefetched one
// chunk ahead; end-of-iter __syncthreads' vmcnt drain covers staging + x.
__global__ __launch_bounds__(512, 2) void lora_phase1(
    const float* __restrict__ x, const float* __restrict__ A,
    const float* __restrict__ B, float* __restrict__ t,
    float* __restrict__ BT)
{
    __shared__ float4 As[2][RANK][64];    // 2 x 16 KB
    const int lane = threadIdx.x & 63;
    const int wave = threadIdx.x >> 6;    // 0..7
    const int row0 = blockIdx.x * 32 + wave * 4;

    const float4* __restrict__ A4 = (const float4*)A;
    const float4* __restrict__ x0 = (const float4*)(x + (size_t)(row0 + 0) * IN_F);
    const float4* __restrict__ x1 = (const float4*)(x + (size_t)(row0 + 1) * IN_F);
    const float4* __restrict__ x2 = (const float4*)(x + (size_t)(row0 + 2) * IN_F);
    const float4* __restrict__ x3 = (const float4*)(x + (size_t)(row0 + 3) * IN_F);

    float acc0[RANK], acc1[RANK], acc2[RANK], acc3[RANK];
#pragma unroll
    for (int r = 0; r < RANK; ++r) {
        acc0[r] = 0.0f; acc1[r] = 0.0f; acc2[r] = 0.0f; acc3[r] = 0.0f;
    }

    // Stage j=0 into buf 0 (wave w -> ranks 2w, 2w+1); prefetch x chunk 0.
#pragma unroll
    for (int rr = 0; rr < 2; ++rr) {
        const int r = wave * 2 + rr;
        __builtin_amdgcn_global_load_lds((as1_cvp)(A4 + (size_t)r * (IN_F / 4) + lane),
                                         (as3_vp)(&As[0][r][0]), 16, 0, 0);
    }
    float4 xc0 = x0[lane];
    float4 xc1 = x1[lane];
    float4 xc2 = x2[lane];
    float4 xc3 = x3[lane];
    __syncthreads();

    int buf = 0;
#pragma unroll 1
    for (int j = 0; j < 16; ++j) {
        float4 xn0, xn1, xn2, xn3;
        if (j < 15) {
            const int c4 = (j + 1) * 64 + lane;
#pragma unroll
            for (int rr = 0; rr < 2; ++rr) {
                const int r = wave * 2 + rr;
                __builtin_amdgcn_global_load_lds(
                    (as1_cvp)(A4 + (size_t)r * (IN_F / 4) + c4),
                    (as3_vp)(&As[buf ^ 1][r][0]), 16, 0, 0);
            }
            xn0 = x0[c4];
            xn1 = x1[c4];
            xn2 = x2[c4];
            xn3 = x3[c4];
        }

#pragma unroll
        for (int r = 0; r < RANK; ++r) {
            const float4 av = As[buf][r][lane];   // ds_read_b128, conflict-free
            acc0[r] += xc0.x * av.x; acc0[r] += xc0.y * av.y;
            acc0[r] += xc0.z * av.z; acc0[r] += xc0.w * av.w;
            acc1[r] += xc1.x * av.x; acc1[r] += xc1.y * av.y;
            acc1[r] += xc1.z * av.z; acc1[r] += xc1.w * av.w;
            acc2[r] += xc2.x * av.x; acc2[r] += xc2.y * av.y;
            acc2[r] += xc2.z * av.z; acc2[r] += xc2.w * av.w;
            acc3[r] += xc3.x * av.x; acc3[r] += xc3.y * av.y;
            acc3[r] += xc3.z * av.z; acc3[r] += xc3.w * av.w;
        }

        if (j < 15) {
            __syncthreads();   // all waves done reading As[buf]; staging drained
            buf ^= 1;
            xc0 = xn0; xc1 = xn1; xc2 = xn2; xc3 = xn3;
        }
    }

    // Cross-lane butterfly reduce (64 lanes) for each of the 4x16 sums.
#pragma unroll
    for (int p = 0; p < 4; ++p) {
        float out_v = 0.0f;
#pragma unroll
        for (int r = 0; r < RANK; ++r) {
            float v = (p == 0) ? acc0[r] : (p == 1) ? acc1[r]
                    : (p == 2) ? acc2[r] : acc3[r];
#pragma unroll
            for (int s = 1; s < 64; s <<= 1)
                v += __shfl_xor(v, s, 64);
            out_v = (lane == r) ? v : out_v;
        }
        if (lane < RANK)
            t[(size_t)(row0 + p) * RANK + lane] = SCALING * out_v;
    }

    // ---- B transpose tail (blocks 0..31): BT[r][o] = B[o][r], 256 KB ----
    // Coalesced float4 stores (lanes contiguous in o); reads are 4 scalar
    // loads/thread from the tiny L2-resident B. ~8 KB/block of extra work.
    if (BT != nullptr && blockIdx.x < 32) {
        const int id = blockIdx.x * 512 + threadIdx.x;   // 0..16383
        const int r  = id >> 10;                         // 0..15
        const int c4 = id & 1023;                        // float4-col in BT row
        f32x4 v;
        v.x = B[(size_t)(4 * c4 + 0) * RANK + r];
        v.y = B[(size_t)(4 * c4 + 1) * RANK + r];
        v.z = B[(size_t)(4 * c4 + 2) * RANK + r];
        v.w = B[(size_t)(4 * c4 + 3) * RANK + r];
        ((f32x4*)BT)[(size_t)r * (OUT_F / 4) + c4] = v;
    }
}

// ---------------- Kernel 2 (BT path): out = t @ B^T + bias ----------------
// block = 256; thread owns 4 cols x 16 rows; grid (4, 512) = 2048 blocks.
// b[16] (lane-contiguous float4 loads from BT) amortized over 16 rows.
__global__ __launch_bounds__(256) void lora_phase2t(
    const float* __restrict__ t, const float* __restrict__ BT,
    const float* __restrict__ bias, float* __restrict__ out)
{
    const int o0 = blockIdx.x * 1024 + threadIdx.x * 4;  // first owned column
    const int m0 = blockIdx.y * 16;                      // first row

    const f32x4* __restrict__ BT4 = (const f32x4*)BT;
    const float4* __restrict__ t4 = (const float4*)t;

    // b[r] = BT[r][o0..o0+3] -- lanes contiguous, coalesced (1 KB/instr)
    f32x4 b[16];
#pragma unroll
    for (int r = 0; r < 16; ++r)
        b[r] = BT4[(size_t)r * (OUT_F / 4) + (o0 >> 2)];

    const f32x4 bs = *(const f32x4*)(bias + o0);

#pragma unroll
    for (int mi = 0; mi < 16; ++mi) {
        // t row (uniform across block -> scalar loads, L2-resident)
        const float4 tv0 = t4[(size_t)(m0 + mi) * 4 + 0];
        const float4 tv1 = t4[(size_t)(m0 + mi) * 4 + 1];
        const float4 tv2 = t4[(size_t)(m0 + mi) * 4 + 2];
        const float4 tv3 = t4[(size_t)(m0 + mi) * 4 + 3];

        f32x4 v = bs;
        v += b[0]  * tv0.x; v += b[1]  * tv0.y; v += b[2]  * tv0.z; v += b[3]  * tv0.w;
        v += b[4]  * tv1.x; v += b[5]  * tv1.y; v += b[6]  * tv1.z; v += b[7]  * tv1.w;
        v += b[8]  * tv2.x; v += b[9]  * tv2.y; v += b[10] * tv2.z; v += b[11] * tv2.w;
        v += b[12] * tv3.x; v += b[13] * tv3.y; v += b[14] * tv3.z; v += b[15] * tv3.w;

        *(f32x4*)(out + (size_t)(m0 + mi) * OUT_F + o0) = v;
    }
}

// ---------------- Kernel 2 (fallback, ws too small): old strided-B ----------
__global__ __launch_bounds__(256) void lora_phase2(
    const float* __restrict__ t, const float* __restrict__ B,
    const float* __restrict__ bias, float* __restrict__ out)
{
    const int o0 = blockIdx.x * 1024 + threadIdx.x * 4;
    const int m0 = blockIdx.y * 4;

    const float4* __restrict__ B4 = (const float4*)B;
    const float4* __restrict__ t4 = (const float4*)t;

    float4 b[4][4];
#pragma unroll
    for (int q = 0; q < 4; ++q)
#pragma unroll
        for (int rr = 0; rr < 4; ++rr)
            b[q][rr] = B4[(size_t)(o0 + q) * 4 + rr];

    float4 tv[4][4];
#pragma unroll
    for (int mi = 0; mi < 4; ++mi)
#pragma unroll
        for (int rr = 0; rr < 4; ++rr)
            tv[mi][rr] = t4[(size_t)(m0 + mi) * 4 + rr];

    const float4 bs = *(const float4*)(bias + o0);

#pragma unroll
    for (int mi = 0; mi < 4; ++mi) {
        float v[4] = {bs.x, bs.y, bs.z, bs.w};
#pragma unroll
        for (int q = 0; q < 4; ++q) {
#pragma unroll
            for (int rr = 0; rr < 4; ++rr) {
                v[q] += b[q][rr].x * tv[mi][rr].x;
                v[q] += b[q][rr].y * tv[mi][rr].y;
                v[q] += b[q][rr].z * tv[mi][rr].z;
                v[q] += b[q][rr].w * tv[mi][rr].w;
            }
        }
        float4 o4 = {v[0], v[1], v[2], v[3]};
        *(float4*)(out + (size_t)(m0 + mi) * OUT_F + o0) = o4;
    }
}

extern "C" void kernel_launch(void* const* d_in, const int* in_sizes, int n_in,
                              void* d_out, int out_size, void* d_ws, size_t ws_size,
                              hipStream_t stream) {
    const float* x    = (const float*)d_in[0];  // [8192, 4096]
    const float* A    = (const float*)d_in[1];  // [16, 4096]
    const float* B    = (const float*)d_in[2];  // [4096, 16]
    const float* bias = (const float*)d_in[3];  // [4096]
    float* out = (float*)d_out;                 // [8192, 4096]
    float* t   = (float*)d_ws;                  // [8192, 16] scratch (512 KB)

    const size_t need_bt = (size_t)(M_TOT * RANK + RANK * OUT_F) * sizeof(float);
    const bool use_bt = ws_size >= need_bt;     // 768 KB
    float* BT = t + (size_t)M_TOT * RANK;       // [16, 4096] (256 KB)

    // Phase 1: t = 2 * x @ A^T  (32 rows/block; B-transpose tail in blocks 0..31)
    lora_phase1<<<dim3(M_TOT / 32), dim3(512), 0, stream>>>(
        x, A, B, t, use_bt ? BT : nullptr);

    // Phase 2: out = t @ B^T + bias
    if (use_bt)
        lora_phase2t<<<dim3(OUT_F / 1024, M_TOT / 16), dim3(256), 0, stream>>>(t, BT, bias, out);
    else
        lora_phase2<<<dim3(OUT_F / 1024, M_TOT / 4), dim3(256), 0, stream>>>(t, B, bias, out);
}